// Round 15
// baseline (2790.717 us; speedup 1.0000x reference)
//
#include <hip/hip_runtime.h>

#define VOCAB 32000
#define EMB   1024
#define HID   1024
#define SEQ   128
#define BATCH 32
#define ROWS  (SEQ * BATCH)   // 4096
#define G4    (4 * HID)       // 4096
#define NCOL  16              // h-cols per block
#define NBLKL 64              // blocks per layer
#define SSEG2 1024            // ushorts per segment: 32 rows x (16 hi + 16 lo)
#define SSLOT 65536           // ushorts per slot: 64 segments (128 KB)

typedef __bf16 bf16x8 __attribute__((ext_vector_type(8)));
typedef float  f32x4  __attribute__((ext_vector_type(4)));

__device__ __forceinline__ unsigned short f2bf(float f) {
  union { float f; unsigned int u; } v; v.f = f;
  unsigned int r = v.u + 0x7fffu + ((v.u >> 16) & 1u);
  return (unsigned short)(r >> 16);
}
__device__ __forceinline__ float bf2f(unsigned short u) {
  union { unsigned int u; float f; } v; v.u = ((unsigned int)u) << 16;
  return v.f;
}

__device__ __forceinline__ void async16(const void* g, void* l) {
  __builtin_amdgcn_global_load_lds(
      (const __attribute__((address_space(1))) void*)g,
      (__attribute__((address_space(3))) void*)l, 16, 0, 0);
}

__device__ __forceinline__ float fsigmoid(float x) {
  return __builtin_amdgcn_rcpf(1.f + __expf(-x));
}
__device__ __forceinline__ float ftanh(float x) {
  return 1.f - 2.f * __builtin_amdgcn_rcpf(__expf(2.f * x) + 1.f);
}

// ------- embedding gather + split, PACKED layout [t][seg=e>>4][row][16h|16l] ----
__global__ void embed_split(const int* __restrict__ ids, const float* __restrict__ emb,
                            unsigned short* __restrict__ Xp) {
  int r = blockIdx.x;                 // t*32 + b
  int t = r >> 5, b = r & 31;
  int row = ids[r];
  int e = threadIdx.x * 4;
  const float4 v = *reinterpret_cast<const float4*>(emb + (size_t)row * EMB + e);
  ushort4 hi, lo;
  hi.x = f2bf(v.x); lo.x = f2bf(v.x - bf2f(hi.x));
  hi.y = f2bf(v.y); lo.y = f2bf(v.y - bf2f(hi.y));
  hi.z = f2bf(v.z); lo.z = f2bf(v.z - bf2f(hi.z));
  hi.w = f2bf(v.w); lo.w = f2bf(v.w - bf2f(hi.w));
  unsigned short* dst = Xp + (size_t)t * SSLOT + (e >> 4) * SSEG2 + b * 32 + (e & 15);
  *reinterpret_cast<ushort4*>(dst)      = hi;
  *reinterpret_cast<ushort4*>(dst + 16) = lo;
}

// ------------- transpose f32 [K][N] -> bf16 [N][K] (Wd, r5-validated) -------
__global__ void transpose_kernel(const float* __restrict__ in, unsigned short* __restrict__ out,
                                 int K, int N) {
  __shared__ float t[32][33];
  int n0 = blockIdx.x * 32, k0 = blockIdx.y * 32;
  int tx = threadIdx.x, ty = threadIdx.y;
#pragma unroll
  for (int i = 0; i < 4; ++i)
    t[ty + i * 8][tx] = in[(size_t)(k0 + ty + i * 8) * N + n0 + tx];
  __syncthreads();
#pragma unroll
  for (int i = 0; i < 4; ++i)
    out[(size_t)(n0 + ty + i * 8) * K + k0 + tx] = f2bf(t[tx][ty + i * 8]);
}

// ============ fused 2-layer LSTM, 64 blocks/layer x 1024 threads (16 waves):
// register-resident split-bf16 W (in-register from raw f32), MFMA z-path,
// packed block-major ring + per-wave 8-producer RELAXED flags (r12 protocol).
__global__ __launch_bounds__(1024, 4) void lstm_ring(
    const unsigned short* __restrict__ Xp,        // [128][64][32][32] packed
    const float* __restrict__ W0, const float* __restrict__ W1,
    const float* __restrict__ b0, const float* __restrict__ b1,
    unsigned short* __restrict__ H2,              // [4096][1024] flat, for gemm
    unsigned short* h1r, unsigned short* h2r,     // rings [129][64][32][32]
    unsigned int* F0, unsigned int* F1)
{
  __shared__ float zl[16][32][68];                // 139 KB padded

  const int tid   = threadIdx.x;
  const int lane  = tid & 63;
  const int w     = tid >> 6;                // wave 0..15, K-slice w*128..+128
  const int layer = blockIdx.x >> 6;
  const int wg    = blockIdx.x & 63;
  const int j0    = wg * NCOL;               // 16 h-cols per block
  const int lrow  = lane & 15;
  const int klo   = (lane >> 4) * 8;

  const float* Wraw = layer ? W1 : W0;
  const float* bias = layer ? b1 : b0;

  // ---- W prologue: hi/lo split in-register from raw f32 W ----
  // wave w covers concat-K [w*128, w*128+128); n in 0..63 -> gate n>>4, col n&15
  bf16x8 wh[4][4], wl[4][4];                 // [nt][ks], 128 VGPR
#pragma unroll
  for (int nt = 0; nt < 4; ++nt) {
    int n   = nt * 16 + lrow;
    int col = (n >> 4) * 1024 + j0 + (n & 15);
#pragma unroll
    for (int ks = 0; ks < 4; ++ks) {
      alignas(16) unsigned short th[8], tl[8];
#pragma unroll
      for (int e = 0; e < 8; ++e) {
        float v = Wraw[(size_t)(w * 128 + ks * 32 + klo + e) * G4 + col];
        th[e] = f2bf(v);
        tl[e] = f2bf(v - bf2f(th[e]));
      }
      wh[nt][ks] = *reinterpret_cast<bf16x8*>(th);
      wl[nt][ks] = *reinterpret_cast<bf16x8*>(tl);
    }
  }

  const int eb = tid >> 4;                   // batch (tid<512)
  const int ec = tid & 15;                   // h-col
  const float bi  = bias[j0 + ec];
  const float bj  = bias[1024 + j0 + ec];
  const float bff = bias[2048 + j0 + ec];
  const float bo  = bias[3072 + j0 + ec];
  float c = 0.f;

  unsigned int* Fown = layer ? F1 : F0;

  for (int t = 0; t < SEQ; ++t) {
    // ---- per-wave wait on the 8 producer blocks of this wave's K-slice ----
    {
      const unsigned int* FF = nullptr;
      unsigned tgt = 0; int fb = 0;
      if (layer == 0) {
        if (w >= 8) { FF = F0; tgt = (unsigned)t; fb = (w - 8) * 8; }
      } else {
        if (w < 8) { FF = F0; tgt = (unsigned)(t + 1); fb = w * 8; }
        else       { FF = F1; tgt = (unsigned)t;       fb = (w - 8) * 8; }
      }
      if (FF && tgt) {
        for (;;) {
          unsigned v = (lane < 8)
              ? __hip_atomic_load(FF + (fb + lane) * 4, __ATOMIC_RELAXED,
                                  __HIP_MEMORY_SCOPE_AGENT)
              : 0xFFFFFFFFu;
          if (__all(v >= tgt)) break;
          __builtin_amdgcn_s_sleep(1);
        }
      }
      __builtin_amdgcn_sched_barrier(0);   // pin: A-loads stay after the poll
    }

    // ---- A source (packed addressing, identical for X and h rings) ----
    const unsigned short* pb;
    if (layer == 0) pb = (w < 8) ? (Xp  + (size_t)t * SSLOT) : (h1r + (size_t)t * SSLOT);
    else            pb = (w < 8) ? (h1r + (size_t)(t + 1) * SSLOT) : (h2r + (size_t)t * SSLOT);
    const int kb = (w & 7) * 128;            // k-slice within the 1024-wide half
    const unsigned short* lanebase =
        pb + (size_t)((kb >> 4) + (klo >> 4)) * SSEG2 + lrow * 32 + (klo & 8);

    f32x4 acc[2][4] = {};
#pragma unroll
    for (int ks = 0; ks < 4; ++ks) {
      const unsigned short* p = lanebase + ks * (2 * SSEG2);
      bf16x8 a0h = *reinterpret_cast<const bf16x8*>(p);          // row lrow
      bf16x8 a0l = *reinterpret_cast<const bf16x8*>(p + 16);
      bf16x8 a1h = *reinterpret_cast<const bf16x8*>(p + 512);    // row lrow+16
      bf16x8 a1l = *reinterpret_cast<const bf16x8*>(p + 528);
#pragma unroll
      for (int nt = 0; nt < 4; ++nt) {
        acc[0][nt] = __builtin_amdgcn_mfma_f32_16x16x32_bf16(a0h, wh[nt][ks], acc[0][nt], 0, 0, 0);
        acc[0][nt] = __builtin_amdgcn_mfma_f32_16x16x32_bf16(a0l, wh[nt][ks], acc[0][nt], 0, 0, 0);
        acc[0][nt] = __builtin_amdgcn_mfma_f32_16x16x32_bf16(a0h, wl[nt][ks], acc[0][nt], 0, 0, 0);
        acc[1][nt] = __builtin_amdgcn_mfma_f32_16x16x32_bf16(a1h, wh[nt][ks], acc[1][nt], 0, 0, 0);
        acc[1][nt] = __builtin_amdgcn_mfma_f32_16x16x32_bf16(a1l, wh[nt][ks], acc[1][nt], 0, 0, 0);
        acc[1][nt] = __builtin_amdgcn_mfma_f32_16x16x32_bf16(a1h, wl[nt][ks], acc[1][nt], 0, 0, 0);
      }
    }

    // C/D (r5-validated): col = lane&15 (n), row = (lane>>4)*4 + j (batch)
    const int zb = (lane >> 4) * 4;
#pragma unroll
    for (int mt = 0; mt < 2; ++mt)
#pragma unroll
      for (int nt = 0; nt < 4; ++nt)
#pragma unroll
        for (int j = 0; j < 4; ++j)
          zl[w][mt * 16 + zb + j][nt * 16 + lrow] = acc[mt][nt][j];
    __syncthreads();

    unsigned short hh = 0;
    if (tid < 512) {
      float iv = bi, jv = bj, fv = bff, ov = bo;
#pragma unroll
      for (int ww = 0; ww < 16; ++ww) {
        iv += zl[ww][eb][ec];
        jv += zl[ww][eb][16 + ec];
        fv += zl[ww][eb][32 + ec];
        ov += zl[ww][eb][48 + ec];
      }
      float si = fsigmoid(iv);
      float sf = fsigmoid(fv + 1.f);     // FORGET_BIAS = 1.0
      float so = fsigmoid(ov);
      float tj = ftanh(jv);
      c = c * sf + si * tj;
      float hv = ftanh(c) * so;
      hh = f2bf(hv);
      unsigned short hl = f2bf(hv - bf2f(hh));
      int hhp = __shfl_xor((int)hh, 1);
      int hlp = __shfl_xor((int)hl, 1);
      if ((ec & 1) == 0) {
        unsigned uhi = (unsigned)hh | ((unsigned)hhp << 16);
        unsigned ulo = (unsigned)hl | ((unsigned)hlp << 16);
        // own segment: contiguous 2KB [32 rows][16 hi u32? -> 8 hi + 8 lo u32/row]
        unsigned int* du = (unsigned int*)((layer ? h2r : h1r)
                           + (size_t)(t + 1) * SSLOT + wg * SSEG2);
        unsigned uoff = (unsigned)(eb * 16 + (ec >> 1));
        __hip_atomic_store(du + uoff,     uhi, __ATOMIC_RELAXED, __HIP_MEMORY_SCOPE_AGENT);
        __hip_atomic_store(du + uoff + 8, ulo, __ATOMIC_RELAXED, __HIP_MEMORY_SCOPE_AGENT);
      }
    }
    __syncthreads();   // drains ring stores (vmcnt=0) + zl reads done
    if (tid == 0)
      __hip_atomic_store(&Fown[wg * 4], (unsigned)(t + 1),
                         __ATOMIC_RELAXED, __HIP_MEMORY_SCOPE_AGENT);
    // off-critical-path flat H2 write for the gemm (next dispatch)
    if (layer && tid < 512)
      H2[(size_t)(t * 32 + eb) * 1024 + j0 + ec] = hh;
  }
}

// -------- MFMA dense GEMM (r14, validated): swizzled 128^2 tile ---------
__global__ __launch_bounds__(256) void gemm_bt(
    const unsigned short* __restrict__ A, const unsigned short* __restrict__ B,
    const float* __restrict__ bias, float* __restrict__ C, int M, int N, int K)
{
  __shared__ __align__(16) unsigned short As[128 * 32];
  __shared__ __align__(16) unsigned short Bs[128 * 32];
  const int tid = threadIdx.x, lane = tid & 63, w = tid >> 6;

  const int ntiles = gridDim.x;
  int lid = blockIdx.y * ntiles + blockIdx.x;
  int total = ntiles * gridDim.y;
  int cpx = total >> 3;
  int swz = (lid & 7) * cpx + (lid >> 3);
  int bn = swz % ntiles, bm = swz / ntiles;

  const int wm = (w >> 1) * 64, wn = (w & 1) * 64;
  const int lrow = lane & 15;
  const int l4 = lane >> 2, l2 = lane & 3;

  f32x4 acc[4][4] = {};

  for (int kt = 0; kt < K / 32; ++kt) {
    __syncthreads();
#pragma unroll
    for (int ci = 0; ci < 2; ++ci) {
      int row = w * 32 + ci * 16 + l4;
      int sw  = l2 ^ ((row >> 1) & 3);          // pre-swizzled source chunk
      async16(A + (size_t)(bm * 128 + row) * K + kt * 32 + sw * 8,
              (char*)As + (w * 2 + ci) * 1024);
      async16(B + (size_t)(bn * 128 + row) * K + kt * 32 + sw * 8,
              (char*)Bs + (w * 2 + ci) * 1024);
    }
    __syncthreads();
    bf16x8 a[4], bb[4];
#pragma unroll
    for (int i = 0; i < 4; ++i) {
      int ra = wm + i * 16 + lrow;
      int rb = wn + i * 16 + lrow;
      a[i]  = *reinterpret_cast<const bf16x8*>(As + ra * 32 + (((lane >> 4) ^ ((ra >> 1) & 3)) * 8));
      bb[i] = *reinterpret_cast<const bf16x8*>(Bs + rb * 32 + (((lane >> 4) ^ ((rb >> 1) & 3)) * 8));
    }
#pragma unroll
    for (int i = 0; i < 4; ++i)
#pragma unroll
      for (int j = 0; j < 4; ++j)
        acc[i][j] = __builtin_amdgcn_mfma_f32_16x16x32_bf16(a[i], bb[j], acc[i][j], 0, 0, 0);
  }

#pragma unroll
  for (int j2 = 0; j2 < 4; ++j2) {
    int col = bn * 128 + wn + j2 * 16 + lrow;
    float bv = bias[col];
#pragma unroll
    for (int i = 0; i < 4; ++i) {
      int rbase = bm * 128 + wm + i * 16 + (lane >> 4) * 4;
#pragma unroll
      for (int j = 0; j < 4; ++j)
        C[(size_t)(rbase + j) * N + col] = acc[i][j2][j] + bv;
    }
  }
}

// ================= host =====================================================
extern "C" void kernel_launch(void* const* d_in, const int* in_sizes, int n_in,
                              void* d_out, int out_size, void* d_ws, size_t ws_size,
                              hipStream_t stream) {
  const int*   ids = (const int*)d_in[0];
  const float* emb = (const float*)d_in[1];
  const float* W0  = (const float*)d_in[2];
  const float* b0  = (const float*)d_in[3];
  const float* W1  = (const float*)d_in[4];
  const float* b1  = (const float*)d_in[5];
  const float* Wd  = (const float*)d_in[6];
  const float* bd  = (const float*)d_in[7];
  float* out = (float*)d_out;

  // d_out scratch (dead before gemm overwrites all of it): packed X + both rings
  unsigned short* Xp  = (unsigned short*)d_out;                 // 128 slots, 16.8 MB
  unsigned short* h1r = Xp + (size_t)SEQ * SSLOT;               // 129 slots, 16.9 MB
  unsigned short* h2r = h1r + (size_t)(SEQ + 1) * SSLOT;        // 129 slots, 16.9 MB

  char* ws = (char*)d_ws;
  size_t off = 0;
  auto alloc = [&](size_t bytes) {
    char* p = ws + off;
    off += (bytes + 255) & ~(size_t)255;
    return p;
  };
  unsigned int*   F0  = (unsigned int*)alloc(2048);             // 64 flags x 16B (pad)
  unsigned int*   F1  = (unsigned int*)alloc(2048);
  unsigned short* H2  = (unsigned short*)alloc((size_t)ROWS * HID * 2);   //  8.4 MB
  unsigned short* Wdt = (unsigned short*)alloc((size_t)VOCAB * HID * 2);  // 65.5 MB
  (void)in_sizes; (void)n_in; (void)out_size; (void)ws_size;    // ws total ~74 MB

  hipMemsetAsync(F0, 0, 4096, stream);                          // F0 + F1
  hipMemsetAsync(h1r, 0, (size_t)SSLOT * 2, stream);            // ring slot 0
  hipMemsetAsync(h2r, 0, (size_t)SSLOT * 2, stream);

  embed_split<<<ROWS, 256, 0, stream>>>(ids, emb, Xp);
  transpose_kernel<<<dim3(VOCAB / 32, HID / 32), dim3(32, 8), 0, stream>>>(Wd, Wdt, HID, VOCAB);

  lstm_ring<<<2 * NBLKL, 1024, 0, stream>>>(Xp, W0, W1, b0, b1, H2, h1r, h2r, F0, F1);

  gemm_bt<<<dim3(VOCAB / 128, ROWS / 128), 256, 0, stream>>>(H2, Wdt, bd, out,
                                                             ROWS, VOCAB, HID);
}